// Round 7
// baseline (602.535 us; speedup 1.0000x reference)
//
#include <hip/hip_runtime.h>
#include <hip/hip_bf16.h>

// Problem constants (fixed by reference): D=4, B=2, S=4096, DIN_S=512, DOUT_S=2048
#define D_   4
#define M_   8192      // B*S
#define K_   2048      // D*DIN_S
#define N_   2048      // DOUT_S
#define DIN  512

typedef __attribute__((ext_vector_type(8))) short  short8v;   // 8 bf16 = 4 VGPRs (MFMA A/B frag)
typedef __attribute__((ext_vector_type(4))) float  f32x4;     // MFMA C/D frag

// fp32 -> bf16, round-to-nearest-even
__device__ __forceinline__ unsigned short f2bf(float f) {
  union { float f; unsigned int u; } v; v.f = f;
  unsigned int u = v.u;
  return (unsigned short)((u + 0x7fffu + ((u >> 16) & 1u)) >> 16);
}

// --- Kernel 1: x [i][m][k] fp32 -> A [m][i*512+k] bf16 (row-major M x K) -----
__global__ __launch_bounds__(256) void convert_x_kernel(const float* __restrict__ x,
                                                        unsigned short* __restrict__ A) {
  unsigned int tid = blockIdx.x * 256u + threadIdx.x;   // [0, M_*K_/8)
  unsigned int kg  = tid & 63u;
  unsigned int i   = (tid >> 6) & 3u;
  unsigned int m   = tid >> 8;
  const float4* src = (const float4*)(x + (size_t)i * ((size_t)M_ * DIN)
                                        + (size_t)m * DIN + (size_t)kg * 8);
  float4 a = src[0];
  float4 b = src[1];
  uint4 pk;
  pk.x = (unsigned int)f2bf(a.x) | ((unsigned int)f2bf(a.y) << 16);
  pk.y = (unsigned int)f2bf(a.z) | ((unsigned int)f2bf(a.w) << 16);
  pk.z = (unsigned int)f2bf(b.x) | ((unsigned int)f2bf(b.y) << 16);
  pk.w = (unsigned int)f2bf(b.z) | ((unsigned int)f2bf(b.w) << 16);
  *(uint4*)(A + (size_t)tid * 8) = pk;
}

// --- Kernel 2: W [d][K][N] fp32 -> Wt [d][N][K] bf16 (transpose + cast) ------
__global__ __launch_bounds__(256) void transpose_w_kernel(const float* __restrict__ W,
                                                          unsigned short* __restrict__ Wt) {
  __shared__ float tile[64][65];
  const int d  = blockIdx.z;
  const int k0 = blockIdx.x * 64;
  const int o0 = blockIdx.y * 64;
  const int t  = threadIdx.x;
  const float* src = W + (size_t)d * ((size_t)K_ * N_) + (size_t)k0 * N_ + o0;
  const int c4 = (t & 15) * 4;
  const int r  = t >> 4;
  #pragma unroll
  for (int j = 0; j < 64; j += 16) {
    float4 v = *(const float4*)(src + (size_t)(r + j) * N_ + c4);
    tile[r + j][c4 + 0] = v.x; tile[r + j][c4 + 1] = v.y;
    tile[r + j][c4 + 2] = v.z; tile[r + j][c4 + 3] = v.w;
  }
  __syncthreads();
  unsigned short* dst = Wt + (size_t)d * ((size_t)N_ * K_);
  const int kk = (t & 7) * 8;
  const int oo = t >> 3;
  #pragma unroll
  for (int p = 0; p < 64; p += 32) {
    const int o = oo + p;
    unsigned short tmp[8];
    #pragma unroll
    for (int i = 0; i < 8; i++) tmp[i] = f2bf(tile[kk + i][o]);
    *(uint4*)(dst + (size_t)(o0 + o) * K_ + k0 + kk) = *(uint4*)tmp;
  }
}

// --- Kernel 3: bf16 MFMA GEMM, dual-block-per-CU pipeline -------------------
// 128x256 tile, BK=32, 256 thr (4 waves, 2Mx2N; per-wave 64x128 output).
// WHY 2 small blocks instead of 1 big one (round-4/5 evidence): with one
// 8-wave block, LDS fragment stream (~1156 cy/CU/tile) and MFMA (~1242 cy)
// SERIALIZE (measured 2516 cy/tile, MfmaUtil 46%) because all waves share one
// barrier domain and cross-tile register prefetch is both barrier-illegal and
// register-walled (acc128+frags48 = 244/256). Two 72-KiB blocks co-reside per
// CU (one wave of each per SIMD) with INDEPENDENT barriers: block X's LDS
// phase overlaps block Y's MFMA phase -> per-pair cost -> max(LDS, MFMA).
//
// LDS map (same verified XOR family, zero conflicts in rounds 0/4): rows are
// pair-packed into 128 B lines (8 chunks of 16 B): line L holds rows {2L,2L+1}
// (chunk c: row parity = c>>2, k-chunk = c&3). A region lines 0-63, B region
// lines 64-191. Chunk c of line L stored at slot c^(L&7); staging keeps the
// GLL dest linear and pre-swizzles the per-lane GLOBAL source
// (lane: line=+lane>>3, slot=lane&7 -> chunk (lane&7)^(lane>>3), static);
// fragment ds_read_b128 applies the same XOR -> 64 lanes hit 64 distinct 16 B
// slots spanning 8 full lines = all banks 2-way (free).
//
// Schedule: ring-3 (3 x 24 KB). Body t: vmcnt(6) [own tile-t GLLs landed,
// tile-t+1's 6 stay in flight], barrier, 6 GLL for tile t+2 (overwrites slot
// of t-1, whose reads all completed before this barrier -> race-free),
// 12 ds_read, setprio(1) 32 MFMA setprio(0). ONE barrier per tile (round 5
// proved extra barriers regress). Counted vmcnt never drains in steady state.
#define GLL16(gp, lp)                                                              \
  __builtin_amdgcn_global_load_lds(                                               \
      (const __attribute__((address_space(1))) void*)(gp),                        \
      (__attribute__((address_space(3))) void*)(lp), 16, 0, 0)

#define NT_    64      // K_/32 K-tiles
#define SLOTE  12288   // elems per ring slot: 192 lines x 64

__global__ __launch_bounds__(256, 2) void gemm_kernel(const unsigned short* __restrict__ A,
                                                      const unsigned short* __restrict__ Bt,
                                                      const float* __restrict__ bias,
                                                      float* __restrict__ C) {
  __shared__ __align__(16) unsigned short sT[3 * SLOTE];   // 72 KiB -> 2 blocks/CU
  const int tid  = threadIdx.x;
  const int w    = tid >> 6;        // wave 0..3
  const int lane = tid & 63;
  const int d    = blockIdx.z;
  // gridDim.x = 8: dispatch-linear id % 8 == blockIdx.x -> XCD k owns N-tile k
  // (Wt slice 256 x 2048 x 2B = 1 MiB, L2-resident per XCD). M walks in sync
  // across XCDs so the A stripe stays L3-hot.
  const int tileN = blockIdx.x * 256;
  const int tileM = blockIdx.y * 128;

  const unsigned short* Bd = Bt + (size_t)d * ((size_t)N_ * K_);

  // ---- staging: 6 GLL16 per wave per K-tile (24 GLL = 192 lines) ----
  // GLL gl (= w*6+g) covers lines 8gl..8gl+7. Lane: line = 8gl + (lane>>3),
  // fetches chunk sc = (lane&7)^(lane>>3) of that line (pre-swizzled source).
  // gl 0-7 = A region (A rows 16gl + 2*(lane>>3) + (sc>>2)), gl 8-23 = B.
  const int lrow = lane >> 3;
  const int sc   = (lane & 7) ^ lrow;
  const int ch   = sc >> 2;             // row parity within the line pair
  const int ck   = (sc & 3) * 8;        // k offset (elems)
  const unsigned short* src[6];
  #pragma unroll
  for (int g = 0; g < 6; ++g) {
    const int gl = w * 6 + g;
    src[g] = (gl < 8)
        ? A  + (size_t)(tileM + gl * 16 + lrow * 2 + ch) * K_ + ck
        : Bd + (size_t)(tileN + (gl - 8) * 16 + lrow * 2 + ch) * K_ + ck;
  }
  unsigned short* lW = sT + w * 3072;   // wave-uniform LDS base (+slot, +g*512)

  // ---- fragment lanes (per-wave 64x128: mi 0..3, ni 0..7) ----
  const int wr = w >> 1;                // 0..1 (M half: 64 rows)
  const int wc = w & 1;                 // 0..1 (N half: 128 cols)
  const int fr = lane & 15;
  const int qw = lane >> 4;
  // row r -> line L=r>>1 (L&7=(fr>>1)&7), chunk (r&1)*4+qw, slot = chunk^(L&7)
  const int xoff = ((((fr & 1) * 4) + qw) ^ ((fr >> 1) & 7)) * 8;
  const int aoff = wr * 2048 + (fr >> 1) * 64 + xoff;           // + mi*512
  const int boff = 4096 + wc * 4096 + (fr >> 1) * 64 + xoff;    // + ni*512

  f32x4 acc[4][8];
  #pragma unroll
  for (int mi = 0; mi < 4; ++mi)
    #pragma unroll
    for (int ni = 0; ni < 8; ++ni)
      acc[mi][ni] = (f32x4){0.f, 0.f, 0.f, 0.f};

#define ISSUE_TILE(tt, ss) do {                                               \
    unsigned short* lb_ = lW + (ss) * SLOTE;                                  \
    const size_t    ko_ = (size_t)(tt) * 32;                                  \
    GLL16(src[0] + ko_, lb_);        GLL16(src[1] + ko_, lb_ +  512);         \
    GLL16(src[2] + ko_, lb_ + 1024); GLL16(src[3] + ko_, lb_ + 1536);         \
    GLL16(src[4] + ko_, lb_ + 2048); GLL16(src[5] + ko_, lb_ + 2560);         \
  } while (0)

#define TILE_BODY(tt, ss, WAITSTR, DOISSUE, ss2) do {                         \
    asm volatile(WAITSTR ::: "memory");                                       \
    __builtin_amdgcn_s_barrier();                                             \
    __builtin_amdgcn_sched_barrier(0);                                        \
    if (DOISSUE) ISSUE_TILE((tt) + 2, ss2);                                   \
    const unsigned short* bT = sT + (ss) * SLOTE;                             \
    short8v af[4], bfv[8];                                                    \
    _Pragma("unroll")                                                         \
    for (int mi = 0; mi < 4; ++mi) af[mi]  = *(const short8v*)(bT + aoff + mi * 512); \
    _Pragma("unroll")                                                         \
    for (int ni = 0; ni < 8; ++ni) bfv[ni] = *(const short8v*)(bT + boff + ni * 512); \
    __builtin_amdgcn_s_setprio(1);                                            \
    _Pragma("unroll")                                                         \
    for (int mi = 0; mi < 4; ++mi)                                            \
      _Pragma("unroll")                                                       \
      for (int ni = 0; ni < 8; ++ni)                                          \
        acc[mi][ni] = __builtin_amdgcn_mfma_f32_16x16x32_bf16(af[mi], bfv[ni],\
                                                              acc[mi][ni], 0, 0, 0); \
    __builtin_amdgcn_s_setprio(0);                                            \
  } while (0)

  // Prologue: fill ring slots 0,1 (12 GLL/wave in flight).
  ISSUE_TILE(0, 0); ISSUE_TILE(1, 1);

  // Main loop, ring-3 statically unrolled. Body t: slot t%3; GLL -> (t+2)%3.
  for (int t3 = 0; t3 < NT_ - 1; t3 += 3) {
    TILE_BODY(t3,     0, "s_waitcnt vmcnt(6)", true,              2);
    TILE_BODY(t3 + 1, 1, "s_waitcnt vmcnt(6)", true,              0);
    TILE_BODY(t3 + 2, 2, "s_waitcnt vmcnt(6)", (t3 + 4) < NT_,    1);
  }
  TILE_BODY(NT_ - 1, 0, "s_waitcnt vmcnt(0)", false, 0);   // 63%3 == 0

#undef TILE_BODY
#undef ISSUE_TILE

  // Epilogue: C/D layout col=lane&15, row=(lane>>4)*4+reg [m89/m91-verified]
  float* Cd       = C + (size_t)d * ((size_t)M_ * N_);
  const float* bd = bias + d * N_;
  #pragma unroll
  for (int ni = 0; ni < 8; ++ni) {
    const int col  = tileN + wc * 128 + ni * 16 + fr;
    const float bv = bd[col];
    #pragma unroll
    for (int mi = 0; mi < 4; ++mi) {
      const int row0 = tileM + wr * 64 + mi * 16 + qw * 4;
      #pragma unroll
      for (int r = 0; r < 4; ++r)
        Cd[(size_t)(row0 + r) * N_ + col] = acc[mi][ni][r] + bv;
    }
  }
}

// --- Fallback: naive fp32 (only if d_ws is too small) ------------------------
__global__ void naive_kernel(const float* __restrict__ x, const float* __restrict__ W,
                             const float* __restrict__ bias, float* __restrict__ y) {
  long idx = (long)blockIdx.x * blockDim.x + threadIdx.x;
  if (idx >= (long)D_ * M_ * N_) return;
  int  n = (int)(idx % N_);
  long t = idx / N_;
  int  m = (int)(t % M_);
  int  d = (int)(t / M_);
  float acc = bias[d * N_ + n];
  const float* wd = W + (size_t)d * ((size_t)K_ * N_);
  for (int i = 0; i < D_; i++) {
    const float* xr = x + (size_t)i * ((size_t)M_ * DIN) + (size_t)m * DIN;
    const float* wr = wd + (size_t)i * ((size_t)DIN * N_) + n;
    #pragma unroll 4
    for (int k = 0; k < DIN; k++) acc += xr[k] * wr[(size_t)k * N_];
  }
  y[idx] = acc;
}

extern "C" void kernel_launch(void* const* d_in, const int* in_sizes, int n_in,
                              void* d_out, int out_size, void* d_ws, size_t ws_size,
                              hipStream_t stream) {
  const float* x    = (const float*)d_in[0];   // [4][2][4096][512] fp32
  const float* W    = (const float*)d_in[1];   // [4][4][512][2048] fp32
  const float* bias = (const float*)d_in[2];   // [4][2048] fp32
  float* out        = (float*)d_out;           // [4][2][4096][2048] fp32

  const size_t a_elems  = (size_t)M_ * K_;
  const size_t wt_elems = (size_t)D_ * N_ * K_;
  const size_t need     = (a_elems + wt_elems) * sizeof(unsigned short);

  if (ws_size >= need) {
    unsigned short* Abf = (unsigned short*)d_ws;
    unsigned short* Wt  = Abf + a_elems;

    convert_x_kernel<<<(M_ * K_ / 8) / 256, 256, 0, stream>>>(x, Abf);

    dim3 tgrid(K_ / 64, N_ / 64, D_);   // (32, 32, 4)
    transpose_w_kernel<<<tgrid, 256, 0, stream>>>(W, Wt);

    dim3 ggrid(N_ / 256, M_ / 128, D_); // (8, 64, 4) = 2048 blocks, 256 thr
    gemm_kernel<<<ggrid, 256, 0, stream>>>(Abf, Wt, bias, out);
  } else {
    long total = (long)D_ * M_ * N_;
    naive_kernel<<<(unsigned int)((total + 255) / 256), 256, 0, stream>>>(x, W, bias, out);
  }
}